// Round 23
// baseline (146.550 us; speedup 1.0000x reference)
//
#include <hip/hip_runtime.h>
#include <hip/hip_bf16.h>
#include <math.h>

#define B_BATCH 4
#define T_LEN   4096
#define D_DIM   1024
#define H_HEADS 16
#define NB_BINS 2049
#define M_ROWS  (B_BATCH * T_LEN)   // 16384

typedef __attribute__((ext_vector_type(8))) short short8;           // 8 bf16
typedef __attribute__((ext_vector_type(8))) unsigned short u16x8;   // 8 u16
typedef __attribute__((ext_vector_type(4))) float f32x4;

__device__ __forceinline__ ushort f2bf(float f) {
    unsigned b = __float_as_uint(f);
    unsigned r = (b + 0x7fffu + ((b >> 16) & 1u)) >> 16;   // RNE
    return (ushort)r;
}
__device__ __forceinline__ float bf2f(ushort u) {
    return __uint_as_float(((unsigned)u) << 16);
}
__device__ __forceinline__ u16x8 pack8(const float4& a, const float4& b) {
    u16x8 o;
    o[0] = f2bf(a.x); o[1] = f2bf(a.y); o[2] = f2bf(a.z); o[3] = f2bf(a.w);
    o[4] = f2bf(b.x); o[5] = f2bf(b.y); o[6] = f2bf(b.z); o[7] = f2bf(b.w);
    return o;
}

// ---------------------------------------------------------------- converts
// merged weight conversion: first n4 blocks handle Wv, rest handle Wo
__global__ void cvt_weights(const float* __restrict__ wv, const float* __restrict__ wo,
                            ushort* __restrict__ wvb, ushort* __restrict__ wob, int n4) {
    int i = blockIdx.x * 256 + threadIdx.x;
    const float* src = (i < n4) ? wv : wo;
    ushort* dst = (i < n4) ? wvb : wob;
    int j = (i < n4) ? i : (i - n4);
    float4 v = ((const float4*)src)[j];
    ushort4 o;
    o.x = f2bf(v.x); o.y = f2bf(v.y); o.z = f2bf(v.z); o.w = f2bf(v.w);
    ((ushort4*)dst)[j] = o;
}

// ---------------------------------------------------------------- tables
__device__ __forceinline__ int drev16(int i) {
    return ((i & 15) << 8) | (i & 0xF0) | (i >> 8);
}

// Filter table (radix-16 digit-reversed, pre-scaled 1/4096) + twiddle table
__global__ void prep_tables(const float* __restrict__ lg, const float* __restrict__ ph,
                            float2* __restrict__ Cdr, float2* __restrict__ tw) {
    int idx = blockIdx.x * 256 + threadIdx.x;
    if (idx < 4096) {
        double th = -2.0 * 3.14159265358979323846 * (double)idx / 4096.0;
        tw[idx] = make_float2((float)cos(th), (float)sin(th));
    }
    if (idx >= H_HEADS * 4096) return;
    int h = idx >> 12, i = idx & 4095;
    int f = drev16(i);
    int fc = (f <= 2048) ? f : (4096 - f);
    float sgn = (f <= 2048) ? 1.f : -1.f;
    float m = expf(lg[h * NB_BINS + fc]) * (1.0f / 4096.0f);
    float p = ph[h * NB_BINS + fc];
    float re = m * __cosf(p), im = sgn * m * __sinf(p);
    if (fc == 0 || fc == 2048) im = 0.f;       // irfft c2r drops DC/Nyquist imag
    Cdr[idx] = make_float2(re, im);
}

// ---------------------------------------------------------------- GEMM 256x256, BK=32, 2-buffer (64 KiB)
// r23: LDS halved 128->64 KiB (BK 64->32, 2 buffers) so TWO blocks co-reside
// per CU (16 waves/CU, VGPR pool 8192 >> 16x228) — inter-block overlap covers
// the barrier/drain stalls a single block cannot. Same r17 1-barrier loop,
// same conflict-free swizzle content@(row,pos)=pos^((row>>1)&3), XCD swizzle.
// BF32: B = f32 x, reg-staged + cvt in-kernel; bid decomp bm=bid%nbm (r20).
// ATR: A = K-major y^T, reg-staged fused transpose (r22).
template<bool RESID, bool BIASROW, bool BF32, bool ATR>
__global__ __launch_bounds__(512, 1) void gemm256(const ushort* __restrict__ A,
        const void* __restrict__ Bv, const float* __restrict__ bias,
        const float* __restrict__ resid, void* __restrict__ Cout,
        int M, int N, int K) {
    __shared__ ushort lds[32768];   // A buf: (t&1)*8192 ; B buf: 16384 + (t&1)*8192
    const int tid  = threadIdx.x;
    const int lane = tid & 63;
    const int wid  = tid >> 6;             // 0..7
    const int wr   = wid >> 2, wc = wid & 3;   // 2M x 4N wave grid
    const int fr   = lane & 15;
    const int nbn  = N >> 8;
    int bid = (int)blockIdx.x;
    bid = (bid & 7) * ((int)gridDim.x >> 3) + (bid >> 3);   // XCD swizzle (grid % 8 == 0)
    int bm, bn;
    if (BF32) { const int nbm = M >> 8; bm = bid % nbm; bn = bid / nbm; }
    else      { bm = bid / nbn; bn = bid % nbn; }
    const int row0 = bm << 8, col0 = bn << 8;
    const int NT = K >> 5;                 // BK=32 tiles

    const ushort* Bu = (const ushort*)Bv;
    const float*  Bf = (const float*)Bv;

    f32x4 acc[8][4];
#pragma unroll
    for (int i = 0; i < 8; i++)
#pragma unroll
        for (int j = 0; j < 4; j++) acc[i][j] = (f32x4){0.f, 0.f, 0.f, 0.f};

    // stage one [256][32] bf16 panel via global_load_lds (row-major A)
    auto stageA = [&](int t) {
        int base = (t & 1) << 13;
        int k0 = t << 5;
#pragma unroll
        for (int i = 0; i < 2; i++) {
            int r = (wid << 5) + (i << 4) + (lane >> 2);
            int c = ((lane & 3) ^ ((lane >> 3) & 3)) << 3;
            const ushort* g = A + (size_t)(row0 + r) * (size_t)K + (size_t)(k0 + c);
            __builtin_amdgcn_global_load_lds(
                (const __attribute__((address_space(1))) void*)g,
                (__attribute__((address_space(3))) void*)&lds[base + (((wid << 1) + i) << 9)],
                16, 0, 0);
        }
    };
    // ATR A path: issue 2 x u16x8 along m for this thread's d-column
    auto issueA_tr = [&](int t, u16x8 aR[2]) {
        int dl = tid & 31;
        int m0 = (tid >> 5) << 4;
        const ushort* g = A + (size_t)((t << 5) + dl) * (size_t)M + (size_t)(row0 + m0);
        aR[0] = *(const u16x8*)g;
        aR[1] = *(const u16x8*)(g + 8);
    };
    // scatter 16 b16 writes: elem(m,d) -> row m, chunk (d>>3)^((m>>1)&3), off d&7
    auto writeA_tr = [&](int t, u16x8 aR[2]) {
        int base = (t & 1) << 13;
        int dl = tid & 31;
        int m0 = (tid >> 5) << 4;
        int ch = dl >> 3, d7 = dl & 7;
#pragma unroll
        for (int j = 0; j < 8; j++) {
            int m = m0 + j;
            lds[base + (m << 5) + ((ch ^ ((m >> 1) & 3)) << 3) + d7] = aR[0][j];
        }
#pragma unroll
        for (int j = 0; j < 8; j++) {
            int m = m0 + 8 + j;
            lds[base + (m << 5) + ((ch ^ ((m >> 1) & 3)) << 3) + d7] = aR[1][j];
        }
    };
    auto stageB = [&](int t) {
        int base = 16384 + ((t & 1) << 13);
        int k0 = t << 5;
#pragma unroll
        for (int i = 0; i < 2; i++) {
            int r = (wid << 5) + (i << 4) + (lane >> 2);
            int c = ((lane & 3) ^ ((lane >> 3) & 3)) << 3;
            const ushort* g = Bu + (size_t)(col0 + r) * (size_t)K + (size_t)(k0 + c);
            __builtin_amdgcn_global_load_lds(
                (const __attribute__((address_space(1))) void*)g,
                (__attribute__((address_space(3))) void*)&lds[base + (((wid << 1) + i) << 9)],
                16, 0, 0);
        }
    };
    // f32 B path: issue 4x float4 for one [256][32] panel into regs
    auto issueB = [&](int t, float4 bR[2][2]) {
#pragma unroll
        for (int i = 0; i < 2; i++) {
            int row = (wid << 5) + (i << 4) + (lane >> 2);
            int cc  = lane & 3;
            const float* g = Bf + (size_t)(col0 + row) * (size_t)K
                           + (size_t)((t << 5) + (cc << 3));
            bR[i][0] = *(const float4*)g;
            bR[i][1] = *(const float4*)(g + 4);
        }
    };
    auto writeB = [&](int t, float4 bR[2][2]) {
        int base = 16384 + ((t & 1) << 13);
#pragma unroll
        for (int i = 0; i < 2; i++) {
            int row = (wid << 5) + (i << 4) + (lane >> 2);
            int cc  = lane & 3;
            int slot = cc ^ ((row >> 1) & 3);
            *(u16x8*)&lds[base + (row << 5) + (slot << 3)] = pack8(bR[i][0], bR[i][1]);
        }
    };
    auto rdfrag = [&](int base, int row) -> short8 {
        int g = (((lane >> 4) ^ ((row >> 1) & 3)) << 3);
        return *(const short8*)&lds[base + (row << 5) + g];
    };

    // prologue: stage tile 0
    if (ATR) { u16x8 aR[2]; issueA_tr(0, aR); writeA_tr(0, aR); }
    else     stageA(0);
    if (BF32) { float4 bR[2][2]; issueB(0, bR); writeB(0, bR); }
    else      stageB(0);
    __syncthreads();

    for (int t = 0; t < NT; ++t) {
        const bool pre = (t + 1) < NT;
        float4 bR[2][2];
        u16x8 aR[2];
        if (pre) {
            if (ATR) issueA_tr(t + 1, aR);
            else     stageA(t + 1);
            if (BF32) issueB(t + 1, bR);
            else      stageB(t + 1);
        }
        const int ab = (t & 1) << 13;
        const int bb = 16384 + ((t & 1) << 13);
        short8 bFr[4], aF[4];
#pragma unroll
        for (int ni = 0; ni < 4; ni++) bFr[ni] = rdfrag(bb, (wc << 6) + (ni << 4) + fr);
#pragma unroll
        for (int mh = 0; mh < 2; mh++) {
#pragma unroll
            for (int mi = 0; mi < 4; mi++)
                aF[mi] = rdfrag(ab, (wr << 7) + (mh << 6) + (mi << 4) + fr);
#pragma unroll
            for (int mi = 0; mi < 4; mi++)
#pragma unroll
                for (int ni = 0; ni < 4; ni++)
                    acc[(mh << 2) + mi][ni] = __builtin_amdgcn_mfma_f32_16x16x32_bf16(
                        aF[mi], bFr[ni], acc[(mh << 2) + mi][ni], 0, 0, 0);
        }
        if (pre) {
            if (ATR)  writeA_tr(t + 1, aR);
            if (BF32) writeB(t + 1, bR);
        }
        __syncthreads();   // drains stages + ds_writes, then barrier
    }

    const int crow = (lane >> 4) << 2;
#pragma unroll
    for (int mi = 0; mi < 8; mi++) {
#pragma unroll
        for (int ni = 0; ni < 4; ni++) {
            int row = row0 + (wr << 7) + (mi << 4) + crow;
            int col = col0 + (wc << 6) + (ni << 4) + fr;
            float bcol = BIASROW ? 0.f : bias[col];
#pragma unroll
            for (int j = 0; j < 4; j++) {
                float v = acc[mi][ni][j] + (BIASROW ? bias[row + j] : bcol);
                size_t off = (size_t)(row + j) * N + col;
                if (RESID) ((float*)Cout)[off] = resid[off] + v;
                else       ((ushort*)Cout)[off] = f2bf(v);
            }
        }
    }
}

// ---------------------------------------------------------------- FFT radix-16
__device__ __forceinline__ float2 cadd(float2 a, float2 b){ return make_float2(a.x+b.x, a.y+b.y); }
__device__ __forceinline__ float2 csub(float2 a, float2 b){ return make_float2(a.x-b.x, a.y-b.y); }
__device__ __forceinline__ float2 jmulp(float2 z){ return make_float2(-z.y, z.x); }        // +j*z
__device__ __forceinline__ float2 cmul(float2 a, float2 b){
    return make_float2(fmaf(a.x,b.x,-a.y*b.y), fmaf(a.x,b.y, a.y*b.x)); }
__device__ __forceinline__ float2 cmulc(float2 a, float2 b){   // a * conj(b)
    return make_float2(fmaf(a.x,b.x, a.y*b.y), fmaf(a.y,b.x,-a.x*b.y)); }

template<int INV>
__device__ __forceinline__ void bf4(float2& a, float2& b, float2& c, float2& d) {
    float2 acp = cadd(a,c), acm = csub(a,c);
    float2 bdp = cadd(b,d), bdm = csub(b,d);
    float2 jb  = jmulp(bdm);
    a = cadd(acp, bdp);
    c = csub(acp, bdp);
    if (INV) { b = cadd(acm, jb); d = csub(acm, jb); }
    else     { b = csub(acm, jb); d = cadd(acm, jb); }
}

#define C16_1 0.9238795325112867f
#define S16_1 0.3826834323650898f
#define R16_2 0.7071067811865476f

// DFT-16: input v[j] natural order; output X[k0+4k1] lands in v[4k0+k1] = v[oidx(k)].
template<int INV>
__device__ __forceinline__ void dft16(float2 v[16]) {
    const float sg = INV ? 1.f : -1.f;
    bf4<INV>(v[0], v[4], v[8],  v[12]);
    bf4<INV>(v[1], v[5], v[9],  v[13]);
    bf4<INV>(v[2], v[6], v[10], v[14]);
    bf4<INV>(v[3], v[7], v[11], v[15]);
    const float2 w1 = make_float2( C16_1, sg*S16_1);
    const float2 w2 = make_float2( R16_2, sg*R16_2);
    const float2 w3 = make_float2( S16_1, sg*C16_1);
    const float2 w6 = make_float2(-R16_2, sg*R16_2);
    const float2 w9 = make_float2(-C16_1,-sg*S16_1);
    v[5]  = cmul(v[5],  w1);
    v[6]  = cmul(v[6],  w2);
    v[7]  = cmul(v[7],  w3);
    v[9]  = cmul(v[9],  w2);
    v[10] = INV ? jmulp(v[10]) : make_float2(v[10].y, -v[10].x);
    v[11] = cmul(v[11], w6);
    v[13] = cmul(v[13], w3);
    v[14] = cmul(v[14], w6);
    v[15] = cmul(v[15], w9);
    bf4<INV>(v[0],  v[1],  v[2],  v[3]);
    bf4<INV>(v[4],  v[5],  v[6],  v[7]);
    bf4<INV>(v[8],  v[9],  v[10], v[11]);
    bf4<INV>(v[12], v[13], v[14], v[15]);
}

__host__ __device__ constexpr int oidx(int r) { return ((r & 3) << 2) | (r >> 2); }

// dft16 with register indices composed with the involution oidx: logical input j
// read from v[oidx(j)]; logical output k lands in v[k]. Removes the u[16] copy.
template<int INV>
__device__ __forceinline__ void dft16p(float2 v[16]) {
    const float sg = INV ? 1.f : -1.f;
    bf4<INV>(v[oidx(0)], v[oidx(4)], v[oidx(8)],  v[oidx(12)]);
    bf4<INV>(v[oidx(1)], v[oidx(5)], v[oidx(9)],  v[oidx(13)]);
    bf4<INV>(v[oidx(2)], v[oidx(6)], v[oidx(10)], v[oidx(14)]);
    bf4<INV>(v[oidx(3)], v[oidx(7)], v[oidx(11)], v[oidx(15)]);
    const float2 w1 = make_float2( C16_1, sg*S16_1);
    const float2 w2 = make_float2( R16_2, sg*R16_2);
    const float2 w3 = make_float2( S16_1, sg*C16_1);
    const float2 w6 = make_float2(-R16_2, sg*R16_2);
    const float2 w9 = make_float2(-C16_1,-sg*S16_1);
    v[oidx(5)]  = cmul(v[oidx(5)],  w1);
    v[oidx(6)]  = cmul(v[oidx(6)],  w2);
    v[oidx(7)]  = cmul(v[oidx(7)],  w3);
    v[oidx(9)]  = cmul(v[oidx(9)],  w2);
    v[oidx(10)] = INV ? jmulp(v[oidx(10)]) : make_float2(v[oidx(10)].y, -v[oidx(10)].x);
    v[oidx(11)] = cmul(v[oidx(11)], w6);
    v[oidx(13)] = cmul(v[oidx(13)], w3);
    v[oidx(14)] = cmul(v[oidx(14)], w6);
    v[oidx(15)] = cmul(v[oidx(15)], w9);
    bf4<INV>(v[oidx(0)],  v[oidx(1)],  v[oidx(2)],  v[oidx(3)]);
    bf4<INV>(v[oidx(4)],  v[oidx(5)],  v[oidx(6)],  v[oidx(7)]);
    bf4<INV>(v[oidx(8)],  v[oidx(9)],  v[oidx(10)], v[oidx(11)]);
    bf4<INV>(v[oidx(12)], v[oidx(13)], v[oidx(14)], v[oidx(15)]);
}

// LDS bank swizzle (involution) for float2 array — round-3 proven.
__device__ __forceinline__ int phz(int t) { return t ^ (((t >> 4) ^ (t >> 8)) & 15); }

// In-register twiddle power tree from w1 = W^t: w_r = W^(t*r).
template<typename F>
__device__ __forceinline__ void tw_powers(float2 w1, F&& apply) {
    apply(1, w1);
    float2 w2 = cmul(w1, w1);   apply(2, w2);
    float2 w3 = cmul(w2, w1);   apply(3, w3);
    float2 w4 = cmul(w2, w2);   apply(4, w4);
    float2 w5 = cmul(w4, w1);   apply(5, w5);
    float2 w6 = cmul(w4, w2);   apply(6, w6);
    float2 w7 = cmul(w4, w3);   apply(7, w7);
    float2 w8 = cmul(w4, w4);   apply(8, w8);
    apply(9,  cmul(w8, w1));
    apply(10, cmul(w8, w2));
    apply(11, cmul(w8, w3));
    apply(12, cmul(w8, w4));
    apply(13, cmul(w8, w5));
    apply(14, cmul(w8, w6));
    apply(15, cmul(w8, w7));
}

// 256 threads, TWO complex streams PER THREAD (r14-proven: no spill). 2x ILP
// per wave, halved barrier count, shared twiddles/filter loads.
__global__ __launch_bounds__(256) void fft16_filter(const ushort* __restrict__ VT,
                                                    ushort* __restrict__ yT,
                                                    const float2* __restrict__ tw,
                                                    const float2* __restrict__ Cdr) {
    __shared__ float2 X[2][4096];
    const int tid = threadIdx.x;
    const int b   = blockIdx.x >> 8;
    const int qb  = blockIdx.x & 255;
    const int d0  = qb << 2;                 // channels d0..d0+3 (2 pairs)
    const int h   = qb >> 4;                 // same head for all 4 channels

    float2 v[2][16];
#pragma unroll
    for (int p = 0; p < 2; p++) {
        const ushort* sRe = VT + (size_t)(d0 + 2 * p) * M_ROWS + b * T_LEN;
        const ushort* sIm = VT + (size_t)(d0 + 2 * p + 1) * M_ROWS + b * T_LEN;
#pragma unroll
        for (int j = 0; j < 16; j++)
            v[p][j] = make_float2(bf2f(sRe[tid + (j << 8)]), bf2f(sIm[tid + (j << 8)]));
    }

    // ---- forward stage 1 (stride 256); twiddle power tree shared by streams
    dft16<0>(v[0]);
    dft16<0>(v[1]);
    {
        float2 w1 = tw[tid];
        tw_powers(w1, [&](int r, float2 w) {
            v[0][oidx(r)] = cmul(v[0][oidx(r)], w);
            v[1][oidx(r)] = cmul(v[1][oidx(r)], w);
        });
    }
#pragma unroll
    for (int r = 0; r < 16; r++) {
        int a = phz(tid + (r << 8));
        X[0][a] = v[0][oidx(r)];
        X[1][a] = v[1][oidx(r)];
    }
    __syncthreads();

    // ---- forward stage 2 (stride 16); exclusive in-place ownership, no mid barrier
    const int p2 = tid & 15, g2 = tid >> 4;
    const int base2 = (g2 << 8) + p2;
#pragma unroll
    for (int j = 0; j < 16; j++) {
        int a = phz(base2 + (j << 4));
        v[0][j] = X[0][a];
        v[1][j] = X[1][a];
    }
    dft16<0>(v[0]);
    dft16<0>(v[1]);
#pragma unroll
    for (int r = 1; r < 16; r++) {
        float2 w = tw[(p2 * r) << 4];
        v[0][oidx(r)] = cmul(v[0][oidx(r)], w);
        v[1][oidx(r)] = cmul(v[1][oidx(r)], w);
    }
#pragma unroll
    for (int r = 0; r < 16; r++) {
        int a = phz(base2 + (r << 4));
        X[0][a] = v[0][oidx(r)];
        X[1][a] = v[1][oidx(r)];
    }
    __syncthreads();

    // ---- fused: forward stage 3 + filter (pre-scaled 1/N) + inverse stage 1
    const int base3 = tid << 4;
#pragma unroll
    for (int j = 0; j < 16; j++) {
        int a = phz(base3 + j);
        v[0][j] = X[0][a];
        v[1][j] = X[1][a];
    }
    dft16<0>(v[0]);
    dft16<0>(v[1]);
    const float2* Ch = Cdr + (h << 12) + base3;
#pragma unroll
    for (int r = 0; r < 16; r++) {
        float2 c = Ch[r];                    // one load, both streams
        v[0][oidx(r)] = cmul(v[0][oidx(r)], c);
        v[1][oidx(r)] = cmul(v[1][oidx(r)], c);
    }
    dft16p<1>(v[0]);                         // output k lands in v[k]
    dft16p<1>(v[1]);
#pragma unroll
    for (int r = 0; r < 16; r++) {
        int a = phz(base3 + r);
        X[0][a] = v[0][r];
        X[1][a] = v[1][r];
    }
    __syncthreads();

    // ---- inverse stage 2 (stride 16): un-twiddle then IDFT; no mid barrier
#pragma unroll
    for (int j = 0; j < 16; j++) {
        int a = phz(base2 + (j << 4));
        v[0][j] = X[0][a];
        v[1][j] = X[1][a];
    }
#pragma unroll
    for (int j = 1; j < 16; j++) {
        float2 w = tw[(p2 * j) << 4];
        v[0][j] = cmulc(v[0][j], w);
        v[1][j] = cmulc(v[1][j], w);
    }
    dft16<1>(v[0]);
    dft16<1>(v[1]);
#pragma unroll
    for (int r = 0; r < 16; r++) {
        int a = phz(base2 + (r << 4));
        X[0][a] = v[0][oidx(r)];
        X[1][a] = v[1][oidx(r)];
    }
    __syncthreads();

    // ---- inverse stage 3 (stride 256): un-twiddle (power tree, conj) + store
#pragma unroll
    for (int j = 0; j < 16; j++) {
        int a = phz(tid + (j << 8));
        v[0][j] = X[0][a];
        v[1][j] = X[1][a];
    }
    {
        float2 w1 = tw[tid];
        tw_powers(w1, [&](int r, float2 w) {
            v[0][r] = cmulc(v[0][r], w);
            v[1][r] = cmulc(v[1][r], w);
        });
    }
    dft16<1>(v[0]);
    dft16<1>(v[1]);
#pragma unroll
    for (int p = 0; p < 2; p++) {
        ushort* dRe = yT + (size_t)(d0 + 2 * p) * M_ROWS + b * T_LEN;
        ushort* dIm = yT + (size_t)(d0 + 2 * p + 1) * M_ROWS + b * T_LEN;
#pragma unroll
        for (int r = 0; r < 16; r++) {
            float2 val = v[p][oidx(r)];
            dRe[tid + (r << 8)] = f2bf(val.x);
            dIm[tid + (r << 8)] = f2bf(val.y);
        }
    }
}

// ---------------------------------------------------------------- launch
extern "C" void kernel_launch(void* const* d_in, const int* in_sizes, int n_in,
                              void* d_out, int out_size, void* d_ws, size_t ws_size,
                              hipStream_t stream) {
    const float* x    = (const float*)d_in[0];
    const float* Wqkv = (const float*)d_in[1];
    const float* bqkv = (const float*)d_in[2];
    const float* Wo   = (const float*)d_in[3];
    const float* bo   = (const float*)d_in[4];
    const float* lg   = (const float*)d_in[5];
    const float* ph   = (const float*)d_in[6];

    char* ws = (char*)d_ws;
    ushort* yT  = (ushort*)ws;                      // 33,554,432 B: y^T (fft output)
    ushort* Wvb = (ushort*)(ws + 33554432);         //  2,097,152 B
    ushort* Wob = (ushort*)(ws + 35651584);         //  2,097,152 B
    float2* tw  = (float2*)(ws + 37748736);         //     32,768 B
    float2* Cdr = (float2*)(ws + 37781504);         //    524,288 B

    ushort* VT  = (ushort*)d_out;                   // [1024][16384] (dead after fft)
    float*  out = (float*)d_out;

    prep_tables<<<(H_HEADS * 4096) / 256, 256, 0, stream>>>(lg, ph, Cdr, tw);
    cvt_weights<<<2 * (1048576 / 4) / 256, 256, 0, stream>>>(
        Wqkv + 2048 * 1024, Wo, Wvb, Wob, 1048576 / 4);

    // V^T[d][m] = sum_k Wv[d,k] x[m,k] + b_qkv[2D+d]  — B = f32 x, converted in-kernel
    gemm256<false, true, true, false><<<(D_DIM / 256) * (M_ROWS / 256), 512, 0, stream>>>(
        Wvb, (const void*)x, bqkv + 2 * D_DIM, nullptr, (void*)VT, D_DIM, M_ROWS, D_DIM);

    // spectral filter along T, coalesced rows: V^T (d_out) -> y^T (ws)
    fft16_filter<<<B_BATCH * (D_DIM / 4), 256, 0, stream>>>(VT, yT, tw, Cdr);

    // out = x + y @ Wo^T + b_o ; A consumed directly from y^T (fused transpose)
    gemm256<true, false, false, true><<<(M_ROWS / 256) * (D_DIM / 256), 512, 0, stream>>>(
        yT, (const void*)Wob, bo, x, (void*)out, M_ROWS, D_DIM, D_DIM);
}

// Round 24
// 144.070 us; speedup vs baseline: 1.0172x; 1.0172x over previous
//
#include <hip/hip_runtime.h>
#include <hip/hip_bf16.h>
#include <math.h>

#define B_BATCH 4
#define T_LEN   4096
#define D_DIM   1024
#define H_HEADS 16
#define NB_BINS 2049
#define M_ROWS  (B_BATCH * T_LEN)   // 16384

typedef __attribute__((ext_vector_type(8))) short short8;           // 8 bf16
typedef __attribute__((ext_vector_type(8))) unsigned short u16x8;   // 8 u16
typedef __attribute__((ext_vector_type(4))) float f32x4;

__device__ __forceinline__ ushort f2bf(float f) {
    unsigned b = __float_as_uint(f);
    unsigned r = (b + 0x7fffu + ((b >> 16) & 1u)) >> 16;   // RNE
    return (ushort)r;
}
__device__ __forceinline__ float bf2f(ushort u) {
    return __uint_as_float(((unsigned)u) << 16);
}
__device__ __forceinline__ u16x8 pack8(const float4& a, const float4& b) {
    u16x8 o;
    o[0] = f2bf(a.x); o[1] = f2bf(a.y); o[2] = f2bf(a.z); o[3] = f2bf(a.w);
    o[4] = f2bf(b.x); o[5] = f2bf(b.y); o[6] = f2bf(b.z); o[7] = f2bf(b.w);
    return o;
}

// ---------------------------------------------------------------- converts
// merged weight conversion: first n4 blocks handle Wv, rest handle Wo
__global__ void cvt_weights(const float* __restrict__ wv, const float* __restrict__ wo,
                            ushort* __restrict__ wvb, ushort* __restrict__ wob, int n4) {
    int i = blockIdx.x * 256 + threadIdx.x;
    const float* src = (i < n4) ? wv : wo;
    ushort* dst = (i < n4) ? wvb : wob;
    int j = (i < n4) ? i : (i - n4);
    float4 v = ((const float4*)src)[j];
    ushort4 o;
    o.x = f2bf(v.x); o.y = f2bf(v.y); o.z = f2bf(v.z); o.w = f2bf(v.w);
    ((ushort4*)dst)[j] = o;
}

// ---------------------------------------------------------------- tables
__device__ __forceinline__ int drev16(int i) {
    return ((i & 15) << 8) | (i & 0xF0) | (i >> 8);
}

// Filter table (radix-16 digit-reversed, pre-scaled 1/4096) + twiddle table
__global__ void prep_tables(const float* __restrict__ lg, const float* __restrict__ ph,
                            float2* __restrict__ Cdr, float2* __restrict__ tw) {
    int idx = blockIdx.x * 256 + threadIdx.x;
    if (idx < 4096) {
        double th = -2.0 * 3.14159265358979323846 * (double)idx / 4096.0;
        tw[idx] = make_float2((float)cos(th), (float)sin(th));
    }
    if (idx >= H_HEADS * 4096) return;
    int h = idx >> 12, i = idx & 4095;
    int f = drev16(i);
    int fc = (f <= 2048) ? f : (4096 - f);
    float sgn = (f <= 2048) ? 1.f : -1.f;
    float m = expf(lg[h * NB_BINS + fc]) * (1.0f / 4096.0f);
    float p = ph[h * NB_BINS + fc];
    float re = m * __cosf(p), im = sgn * m * __sinf(p);
    if (fc == 0 || fc == 2048) im = 0.f;       // irfft c2r drops DC/Nyquist imag
    Cdr[idx] = make_float2(re, im);
}

// ---------------------------------------------------------------- GEMM 256x256, BK=64, barrier-minimal
// r17 loop (ONE __syncthreads per BK=64 tile); conflict-free swizzle invariant
// content@(row,pos)=pos^((row>>1)&3); XCD swizzle. BF32: B source f32 (x),
// reg-staged + cvt in-kernel (r18). BF32 bid decomp bm=bid%nbm (r20, L2 reuse).
// ATR (r22): A source is K-major y^T[d][m] — reg-staged fused transpose.
// r23 lesson: BK=32/2-buf (64 KiB) did NOT raise occupancy (still 1 block/CU)
// and doubled barrier events -> regressed. 128 KiB / BK=64 is the optimum.
template<bool RESID, bool BIASROW, bool BF32, bool ATR>
__global__ __launch_bounds__(512, 1) void gemm256(const ushort* __restrict__ A,
        const void* __restrict__ Bv, const float* __restrict__ bias,
        const float* __restrict__ resid, void* __restrict__ Cout,
        int M, int N, int K) {
    __shared__ ushort lds[65536];   // A halves: (d*2+s)*8192 ; B: 32768 + (d*2+s)*8192
    const int tid  = threadIdx.x;
    const int lane = tid & 63;
    const int wid  = tid >> 6;             // 0..7
    const int wr   = wid >> 2, wc = wid & 3;   // 2M x 4N wave grid
    const int fr   = lane & 15;
    const int nbn  = N >> 8;
    int bid = (int)blockIdx.x;
    bid = (bid & 7) * ((int)gridDim.x >> 3) + (bid >> 3);   // XCD swizzle (grid % 8 == 0)
    int bm, bn;
    if (BF32) { const int nbm = M >> 8; bm = bid % nbm; bn = bid / nbm; }
    else      { bm = bid / nbn; bn = bid % nbn; }
    const int row0 = bm << 8, col0 = bn << 8;
    const int NT = K >> 6;                 // BK=64 tiles

    const ushort* Bu = (const ushort*)Bv;
    const float*  Bf = (const float*)Bv;

    f32x4 acc[8][4];
#pragma unroll
    for (int i = 0; i < 8; i++)
#pragma unroll
        for (int j = 0; j < 4; j++) acc[i][j] = (f32x4){0.f, 0.f, 0.f, 0.f};

    // stage one [256][32] bf16 half-panel via global_load_lds (row-major A)
    auto stageA = [&](int t, int s) {
        int base = (((t & 1) << 1) + s) << 13;
        int k0 = (t << 6) + (s << 5);
#pragma unroll
        for (int i = 0; i < 2; i++) {
            int r = (wid << 5) + (i << 4) + (lane >> 2);
            int c = ((lane & 3) ^ ((lane >> 3) & 3)) << 3;
            const ushort* g = A + (size_t)(row0 + r) * (size_t)K + (size_t)(k0 + c);
            __builtin_amdgcn_global_load_lds(
                (const __attribute__((address_space(1))) void*)g,
                (__attribute__((address_space(3))) void*)&lds[base + (((wid << 1) + i) << 9)],
                16, 0, 0);
        }
    };
    // ATR A path: issue 2 x u16x8 along m for this thread's d-column
    auto issueA_tr = [&](int t, int s, u16x8 aR[2]) {
        int dl = tid & 31;                 // d within half
        int m0 = (tid >> 5) << 4;          // 16-row segment
        const ushort* g = A + (size_t)((t << 6) + (s << 5) + dl) * (size_t)M
                        + (size_t)(row0 + m0);
        aR[0] = *(const u16x8*)g;
        aR[1] = *(const u16x8*)(g + 8);
    };
    // scatter 16 b16 writes into swizzled layout: elem(m,d) -> row m,
    // chunk pos = (d>>3)^((m>>1)&3), offset d&7
    auto writeA_tr = [&](int t, int s, u16x8 aR[2]) {
        int base = (((t & 1) << 1) + s) << 13;
        int dl = tid & 31;
        int m0 = (tid >> 5) << 4;
        int ch = dl >> 3, d7 = dl & 7;
#pragma unroll
        for (int j = 0; j < 8; j++) {
            int m = m0 + j;
            lds[base + (m << 5) + ((ch ^ ((m >> 1) & 3)) << 3) + d7] = aR[0][j];
        }
#pragma unroll
        for (int j = 0; j < 8; j++) {
            int m = m0 + 8 + j;
            lds[base + (m << 5) + ((ch ^ ((m >> 1) & 3)) << 3) + d7] = aR[1][j];
        }
    };
    auto stageB = [&](int t, int s) {
        int base = 32768 + ((((t & 1) << 1) + s) << 13);
        int k0 = (t << 6) + (s << 5);
#pragma unroll
        for (int i = 0; i < 2; i++) {
            int r = (wid << 5) + (i << 4) + (lane >> 2);
            int c = ((lane & 3) ^ ((lane >> 3) & 3)) << 3;
            const ushort* g = Bu + (size_t)(col0 + r) * (size_t)K + (size_t)(k0 + c);
            __builtin_amdgcn_global_load_lds(
                (const __attribute__((address_space(1))) void*)g,
                (__attribute__((address_space(3))) void*)&lds[base + (((wid << 1) + i) << 9)],
                16, 0, 0);
        }
    };
    // f32 B path: issue 4x float4 for one half-panel into regs
    auto issueB = [&](int t, int s, float4 bR[2][2]) {
#pragma unroll
        for (int i = 0; i < 2; i++) {
            int row = (wid << 5) + (i << 4) + (lane >> 2);
            int cc  = lane & 3;
            const float* g = Bf + (size_t)(col0 + row) * (size_t)K
                           + (size_t)((t << 6) + (s << 5) + (cc << 3));
            bR[i][0] = *(const float4*)g;
            bR[i][1] = *(const float4*)(g + 4);
        }
    };
    auto writeB = [&](int t, int s, float4 bR[2][2]) {
        int base = 32768 + ((((t & 1) << 1) + s) << 13);
#pragma unroll
        for (int i = 0; i < 2; i++) {
            int row = (wid << 5) + (i << 4) + (lane >> 2);
            int cc  = lane & 3;
            int slot = cc ^ ((row >> 1) & 3);
            *(u16x8*)&lds[base + (row << 5) + (slot << 3)] = pack8(bR[i][0], bR[i][1]);
        }
    };
    auto rdfrag = [&](int base, int row) -> short8 {
        int g = (((lane >> 4) ^ ((row >> 1) & 3)) << 3);
        return *(const short8*)&lds[base + (row << 5) + g];
    };

    // prologue: stage tile 0
    if (ATR) {
        u16x8 aR0[2], aR1[2];
        issueA_tr(0, 0, aR0); issueA_tr(0, 1, aR1);
        writeA_tr(0, 0, aR0); writeA_tr(0, 1, aR1);
    } else {
        stageA(0, 0); stageA(0, 1);
    }
    if (BF32) {
        float4 bR0[2][2], bR1[2][2];
        issueB(0, 0, bR0); issueB(0, 1, bR1);
        writeB(0, 0, bR0); writeB(0, 1, bR1);
    } else {
        stageB(0, 0); stageB(0, 1);
    }
    __syncthreads();

    for (int t = 0; t < NT; ++t) {
        const int d = t & 1;
        const bool pre = (t + 1) < NT;
        float4 bR[2][2];
        u16x8 aR[2];
        if (pre) {
            if (ATR) issueA_tr(t + 1, 0, aR);
            else { stageA(t + 1, 0); stageA(t + 1, 1); }
            if (BF32) issueB(t + 1, 0, bR);
            else { stageB(t + 1, 0); stageB(t + 1, 1); }
        }
        // ---- ks = 0
        {
            const int ab = (((d << 1) + 0) << 13);
            const int bb = 32768 + (((d << 1) + 0) << 13);
            short8 bFr[4], aF[4];
#pragma unroll
            for (int ni = 0; ni < 4; ni++) bFr[ni] = rdfrag(bb, (wc << 6) + (ni << 4) + fr);
#pragma unroll
            for (int mh = 0; mh < 2; mh++) {
#pragma unroll
                for (int mi = 0; mi < 4; mi++)
                    aF[mi] = rdfrag(ab, (wr << 7) + (mh << 6) + (mi << 4) + fr);
#pragma unroll
                for (int mi = 0; mi < 4; mi++)
#pragma unroll
                    for (int ni = 0; ni < 4; ni++)
                        acc[(mh << 2) + mi][ni] = __builtin_amdgcn_mfma_f32_16x16x32_bf16(
                            aF[mi], bFr[ni], acc[(mh << 2) + mi][ni], 0, 0, 0);
            }
        }
        if (pre) {
            if (ATR) { writeA_tr(t + 1, 0, aR); issueA_tr(t + 1, 1, aR); }
            if (BF32) { writeB(t + 1, 0, bR); issueB(t + 1, 1, bR); }
        }
        // ---- ks = 1
        {
            const int ab = (((d << 1) + 1) << 13);
            const int bb = 32768 + (((d << 1) + 1) << 13);
            short8 bFr[4], aF[4];
#pragma unroll
            for (int ni = 0; ni < 4; ni++) bFr[ni] = rdfrag(bb, (wc << 6) + (ni << 4) + fr);
#pragma unroll
            for (int mh = 0; mh < 2; mh++) {
#pragma unroll
                for (int mi = 0; mi < 4; mi++)
                    aF[mi] = rdfrag(ab, (wr << 7) + (mh << 6) + (mi << 4) + fr);
#pragma unroll
                for (int mi = 0; mi < 4; mi++)
#pragma unroll
                    for (int ni = 0; ni < 4; ni++)
                        acc[(mh << 2) + mi][ni] = __builtin_amdgcn_mfma_f32_16x16x32_bf16(
                            aF[mi], bFr[ni], acc[(mh << 2) + mi][ni], 0, 0, 0);
            }
        }
        if (pre) {
            if (ATR) writeA_tr(t + 1, 1, aR);
            if (BF32) writeB(t + 1, 1, bR);
        }
        __syncthreads();   // drains stages + ds_writes, then barrier
    }

    const int crow = (lane >> 4) << 2;
#pragma unroll
    for (int mi = 0; mi < 8; mi++) {
#pragma unroll
        for (int ni = 0; ni < 4; ni++) {
            int row = row0 + (wr << 7) + (mi << 4) + crow;
            int col = col0 + (wc << 6) + (ni << 4) + fr;
            float bcol = BIASROW ? 0.f : bias[col];
#pragma unroll
            for (int j = 0; j < 4; j++) {
                float v = acc[mi][ni][j] + (BIASROW ? bias[row + j] : bcol);
                size_t off = (size_t)(row + j) * N + col;
                if (RESID) ((float*)Cout)[off] = resid[off] + v;
                else       ((ushort*)Cout)[off] = f2bf(v);
            }
        }
    }
}

// ---------------------------------------------------------------- FFT radix-16
__device__ __forceinline__ float2 cadd(float2 a, float2 b){ return make_float2(a.x+b.x, a.y+b.y); }
__device__ __forceinline__ float2 csub(float2 a, float2 b){ return make_float2(a.x-b.x, a.y-b.y); }
__device__ __forceinline__ float2 jmulp(float2 z){ return make_float2(-z.y, z.x); }        // +j*z
__device__ __forceinline__ float2 cmul(float2 a, float2 b){
    return make_float2(fmaf(a.x,b.x,-a.y*b.y), fmaf(a.x,b.y, a.y*b.x)); }
__device__ __forceinline__ float2 cmulc(float2 a, float2 b){   // a * conj(b)
    return make_float2(fmaf(a.x,b.x, a.y*b.y), fmaf(a.y,b.x,-a.x*b.y)); }

template<int INV>
__device__ __forceinline__ void bf4(float2& a, float2& b, float2& c, float2& d) {
    float2 acp = cadd(a,c), acm = csub(a,c);
    float2 bdp = cadd(b,d), bdm = csub(b,d);
    float2 jb  = jmulp(bdm);
    a = cadd(acp, bdp);
    c = csub(acp, bdp);
    if (INV) { b = cadd(acm, jb); d = csub(acm, jb); }
    else     { b = csub(acm, jb); d = cadd(acm, jb); }
}

#define C16_1 0.9238795325112867f
#define S16_1 0.3826834323650898f
#define R16_2 0.7071067811865476f

// DFT-16: input v[j] natural order; output X[k0+4k1] lands in v[4k0+k1] = v[oidx(k)].
template<int INV>
__device__ __forceinline__ void dft16(float2 v[16]) {
    const float sg = INV ? 1.f : -1.f;
    bf4<INV>(v[0], v[4], v[8],  v[12]);
    bf4<INV>(v[1], v[5], v[9],  v[13]);
    bf4<INV>(v[2], v[6], v[10], v[14]);
    bf4<INV>(v[3], v[7], v[11], v[15]);
    const float2 w1 = make_float2( C16_1, sg*S16_1);
    const float2 w2 = make_float2( R16_2, sg*R16_2);
    const float2 w3 = make_float2( S16_1, sg*C16_1);
    const float2 w6 = make_float2(-R16_2, sg*R16_2);
    const float2 w9 = make_float2(-C16_1,-sg*S16_1);
    v[5]  = cmul(v[5],  w1);
    v[6]  = cmul(v[6],  w2);
    v[7]  = cmul(v[7],  w3);
    v[9]  = cmul(v[9],  w2);
    v[10] = INV ? jmulp(v[10]) : make_float2(v[10].y, -v[10].x);
    v[11] = cmul(v[11], w6);
    v[13] = cmul(v[13], w3);
    v[14] = cmul(v[14], w6);
    v[15] = cmul(v[15], w9);
    bf4<INV>(v[0],  v[1],  v[2],  v[3]);
    bf4<INV>(v[4],  v[5],  v[6],  v[7]);
    bf4<INV>(v[8],  v[9],  v[10], v[11]);
    bf4<INV>(v[12], v[13], v[14], v[15]);
}

__host__ __device__ constexpr int oidx(int r) { return ((r & 3) << 2) | (r >> 2); }

// dft16 with register indices composed with the involution oidx: logical input j
// read from v[oidx(j)]; logical output k lands in v[k]. Removes the u[16] copy.
template<int INV>
__device__ __forceinline__ void dft16p(float2 v[16]) {
    const float sg = INV ? 1.f : -1.f;
    bf4<INV>(v[oidx(0)], v[oidx(4)], v[oidx(8)],  v[oidx(12)]);
    bf4<INV>(v[oidx(1)], v[oidx(5)], v[oidx(9)],  v[oidx(13)]);
    bf4<INV>(v[oidx(2)], v[oidx(6)], v[oidx(10)], v[oidx(14)]);
    bf4<INV>(v[oidx(3)], v[oidx(7)], v[oidx(11)], v[oidx(15)]);
    const float2 w1 = make_float2( C16_1, sg*S16_1);
    const float2 w2 = make_float2( R16_2, sg*R16_2);
    const float2 w3 = make_float2( S16_1, sg*C16_1);
    const float2 w6 = make_float2(-R16_2, sg*R16_2);
    const float2 w9 = make_float2(-C16_1,-sg*S16_1);
    v[oidx(5)]  = cmul(v[oidx(5)],  w1);
    v[oidx(6)]  = cmul(v[oidx(6)],  w2);
    v[oidx(7)]  = cmul(v[oidx(7)],  w3);
    v[oidx(9)]  = cmul(v[oidx(9)],  w2);
    v[oidx(10)] = INV ? jmulp(v[oidx(10)]) : make_float2(v[oidx(10)].y, -v[oidx(10)].x);
    v[oidx(11)] = cmul(v[oidx(11)], w6);
    v[oidx(13)] = cmul(v[oidx(13)], w3);
    v[oidx(14)] = cmul(v[oidx(14)], w6);
    v[oidx(15)] = cmul(v[oidx(15)], w9);
    bf4<INV>(v[oidx(0)],  v[oidx(1)],  v[oidx(2)],  v[oidx(3)]);
    bf4<INV>(v[oidx(4)],  v[oidx(5)],  v[oidx(6)],  v[oidx(7)]);
    bf4<INV>(v[oidx(8)],  v[oidx(9)],  v[oidx(10)], v[oidx(11)]);
    bf4<INV>(v[oidx(12)], v[oidx(13)], v[oidx(14)], v[oidx(15)]);
}

// LDS bank swizzle (involution) for float2 array — round-3 proven.
__device__ __forceinline__ int phz(int t) { return t ^ (((t >> 4) ^ (t >> 8)) & 15); }

// In-register twiddle power tree from w1 = W^t: w_r = W^(t*r).
template<typename F>
__device__ __forceinline__ void tw_powers(float2 w1, F&& apply) {
    apply(1, w1);
    float2 w2 = cmul(w1, w1);   apply(2, w2);
    float2 w3 = cmul(w2, w1);   apply(3, w3);
    float2 w4 = cmul(w2, w2);   apply(4, w4);
    float2 w5 = cmul(w4, w1);   apply(5, w5);
    float2 w6 = cmul(w4, w2);   apply(6, w6);
    float2 w7 = cmul(w4, w3);   apply(7, w7);
    float2 w8 = cmul(w4, w4);   apply(8, w8);
    apply(9,  cmul(w8, w1));
    apply(10, cmul(w8, w2));
    apply(11, cmul(w8, w3));
    apply(12, cmul(w8, w4));
    apply(13, cmul(w8, w5));
    apply(14, cmul(w8, w6));
    apply(15, cmul(w8, w7));
}

// 256 threads, TWO complex streams PER THREAD (r14-proven: no spill). 2x ILP
// per wave, halved barrier count, shared twiddles/filter loads.
__global__ __launch_bounds__(256) void fft16_filter(const ushort* __restrict__ VT,
                                                    ushort* __restrict__ yT,
                                                    const float2* __restrict__ tw,
                                                    const float2* __restrict__ Cdr) {
    __shared__ float2 X[2][4096];
    const int tid = threadIdx.x;
    const int b   = blockIdx.x >> 8;
    const int qb  = blockIdx.x & 255;
    const int d0  = qb << 2;                 // channels d0..d0+3 (2 pairs)
    const int h   = qb >> 4;                 // same head for all 4 channels

    float2 v[2][16];
#pragma unroll
    for (int p = 0; p < 2; p++) {
        const ushort* sRe = VT + (size_t)(d0 + 2 * p) * M_ROWS + b * T_LEN;
        const ushort* sIm = VT + (size_t)(d0 + 2 * p + 1) * M_ROWS + b * T_LEN;
#pragma unroll
        for (int j = 0; j < 16; j++)
            v[p][j] = make_float2(bf2f(sRe[tid + (j << 8)]), bf2f(sIm[tid + (j << 8)]));
    }

    // ---- forward stage 1 (stride 256); twiddle power tree shared by streams
    dft16<0>(v[0]);
    dft16<0>(v[1]);
    {
        float2 w1 = tw[tid];
        tw_powers(w1, [&](int r, float2 w) {
            v[0][oidx(r)] = cmul(v[0][oidx(r)], w);
            v[1][oidx(r)] = cmul(v[1][oidx(r)], w);
        });
    }
#pragma unroll
    for (int r = 0; r < 16; r++) {
        int a = phz(tid + (r << 8));
        X[0][a] = v[0][oidx(r)];
        X[1][a] = v[1][oidx(r)];
    }
    __syncthreads();

    // ---- forward stage 2 (stride 16); exclusive in-place ownership, no mid barrier
    const int p2 = tid & 15, g2 = tid >> 4;
    const int base2 = (g2 << 8) + p2;
#pragma unroll
    for (int j = 0; j < 16; j++) {
        int a = phz(base2 + (j << 4));
        v[0][j] = X[0][a];
        v[1][j] = X[1][a];
    }
    dft16<0>(v[0]);
    dft16<0>(v[1]);
#pragma unroll
    for (int r = 1; r < 16; r++) {
        float2 w = tw[(p2 * r) << 4];
        v[0][oidx(r)] = cmul(v[0][oidx(r)], w);
        v[1][oidx(r)] = cmul(v[1][oidx(r)], w);
    }
#pragma unroll
    for (int r = 0; r < 16; r++) {
        int a = phz(base2 + (r << 4));
        X[0][a] = v[0][oidx(r)];
        X[1][a] = v[1][oidx(r)];
    }
    __syncthreads();

    // ---- fused: forward stage 3 + filter (pre-scaled 1/N) + inverse stage 1
    const int base3 = tid << 4;
#pragma unroll
    for (int j = 0; j < 16; j++) {
        int a = phz(base3 + j);
        v[0][j] = X[0][a];
        v[1][j] = X[1][a];
    }
    dft16<0>(v[0]);
    dft16<0>(v[1]);
    const float2* Ch = Cdr + (h << 12) + base3;
#pragma unroll
    for (int r = 0; r < 16; r++) {
        float2 c = Ch[r];                    // one load, both streams
        v[0][oidx(r)] = cmul(v[0][oidx(r)], c);
        v[1][oidx(r)] = cmul(v[1][oidx(r)], c);
    }
    dft16p<1>(v[0]);                         // output k lands in v[k]
    dft16p<1>(v[1]);
#pragma unroll
    for (int r = 0; r < 16; r++) {
        int a = phz(base3 + r);
        X[0][a] = v[0][r];
        X[1][a] = v[1][r];
    }
    __syncthreads();

    // ---- inverse stage 2 (stride 16): un-twiddle then IDFT; no mid barrier
#pragma unroll
    for (int j = 0; j < 16; j++) {
        int a = phz(base2 + (j << 4));
        v[0][j] = X[0][a];
        v[1][j] = X[1][a];
    }
#pragma unroll
    for (int j = 1; j < 16; j++) {
        float2 w = tw[(p2 * j) << 4];
        v[0][j] = cmulc(v[0][j], w);
        v[1][j] = cmulc(v[1][j], w);
    }
    dft16<1>(v[0]);
    dft16<1>(v[1]);
#pragma unroll
    for (int r = 0; r < 16; r++) {
        int a = phz(base2 + (r << 4));
        X[0][a] = v[0][oidx(r)];
        X[1][a] = v[1][oidx(r)];
    }
    __syncthreads();

    // ---- inverse stage 3 (stride 256): un-twiddle (power tree, conj) + store
#pragma unroll
    for (int j = 0; j < 16; j++) {
        int a = phz(tid + (j << 8));
        v[0][j] = X[0][a];
        v[1][j] = X[1][a];
    }
    {
        float2 w1 = tw[tid];
        tw_powers(w1, [&](int r, float2 w) {
            v[0][r] = cmulc(v[0][r], w);
            v[1][r] = cmulc(v[1][r], w);
        });
    }
    dft16<1>(v[0]);
    dft16<1>(v[1]);
#pragma unroll
    for (int p = 0; p < 2; p++) {
        ushort* dRe = yT + (size_t)(d0 + 2 * p) * M_ROWS + b * T_LEN;
        ushort* dIm = yT + (size_t)(d0 + 2 * p + 1) * M_ROWS + b * T_LEN;
#pragma unroll
        for (int r = 0; r < 16; r++) {
            float2 val = v[p][oidx(r)];
            dRe[tid + (r << 8)] = f2bf(val.x);
            dIm[tid + (r << 8)] = f2bf(val.y);
        }
    }
}

// ---------------------------------------------------------------- launch
extern "C" void kernel_launch(void* const* d_in, const int* in_sizes, int n_in,
                              void* d_out, int out_size, void* d_ws, size_t ws_size,
                              hipStream_t stream) {
    const float* x    = (const float*)d_in[0];
    const float* Wqkv = (const float*)d_in[1];
    const float* bqkv = (const float*)d_in[2];
    const float* Wo   = (const float*)d_in[3];
    const float* bo   = (const float*)d_in[4];
    const float* lg   = (const float*)d_in[5];
    const float* ph   = (const float*)d_in[6];

    char* ws = (char*)d_ws;
    ushort* yT  = (ushort*)ws;                      // 33,554,432 B: y^T (fft output)
    ushort* Wvb = (ushort*)(ws + 33554432);         //  2,097,152 B
    ushort* Wob = (ushort*)(ws + 35651584);         //  2,097,152 B
    float2* tw  = (float2*)(ws + 37748736);         //     32,768 B
    float2* Cdr = (float2*)(ws + 37781504);         //    524,288 B

    ushort* VT  = (ushort*)d_out;                   // [1024][16384] (dead after fft)
    float*  out = (float*)d_out;

    prep_tables<<<(H_HEADS * 4096) / 256, 256, 0, stream>>>(lg, ph, Cdr, tw);
    cvt_weights<<<2 * (1048576 / 4) / 256, 256, 0, stream>>>(
        Wqkv + 2048 * 1024, Wo, Wvb, Wob, 1048576 / 4);

    // V^T[d][m] = sum_k Wv[d,k] x[m,k] + b_qkv[2D+d]  — B = f32 x, converted in-kernel
    gemm256<false, true, true, false><<<(D_DIM / 256) * (M_ROWS / 256), 512, 0, stream>>>(
        Wvb, (const void*)x, bqkv + 2 * D_DIM, nullptr, (void*)VT, D_DIM, M_ROWS, D_DIM);

    // spectral filter along T, coalesced rows: V^T (d_out) -> y^T (ws)
    fft16_filter<<<B_BATCH * (D_DIM / 4), 256, 0, stream>>>(VT, yT, tw, Cdr);

    // out = x + y @ Wo^T + b_o ; A consumed directly from y^T (fused transpose)
    gemm256<true, false, false, true><<<(M_ROWS / 256) * (D_DIM / 256), 512, 0, stream>>>(
        yT, (const void*)Wob, bo, x, (void*)out, M_ROWS, D_DIM, D_DIM);
}